// Round 3
// baseline (699.145 us; speedup 1.0000x reference)
//
#include <hip/hip_runtime.h>
#include <hip/hip_bf16.h>

#define NN 4096
#define IN_DIM 512
#define HID 256
#define OUT_DIM 128
#define MAXDEG 192
#define INV_GAMMA (1.0f / 6.0f)
#define LAM 0.11111111111111116f   // 1/0.9 - 1
#define PROP_STEPS 10

// ---------------------------------------------------------------------------
// Dense A scan: per-row adjacency list (ushort, stride MAXDEG), degree,
// D = rowsum+1 (self loop), 1/D, 1/sqrt(D).  One wave per row, deterministic
// ballot-compaction (no atomics).
__global__ void k_analyze(const float* __restrict__ A, unsigned short* __restrict__ cols,
                          int* __restrict__ deg, float* __restrict__ DsqInv,
                          float* __restrict__ Dinv) {
    int wid = threadIdx.x >> 6, lane = threadIdx.x & 63;
    int row = blockIdx.x * 4 + wid;
    const float* Ar = A + (size_t)row * NN;
    unsigned short* crow = cols + (size_t)row * MAXDEG;
    int cnt = 0;
    float fsum = 0.f;
    for (int base = 0; base < NN; base += 64) {
        float a = Ar[base + lane];
        fsum += a;
        bool nz = (a != 0.0f);
        unsigned long long m = __ballot(nz);
        if (nz) {
            int off = cnt + __popcll(m & ((1ull << lane) - 1ull));
            if (off < MAXDEG) crow[off] = (unsigned short)(base + lane);
        }
        cnt += __popcll(m);
    }
#pragma unroll
    for (int m = 1; m < 64; m <<= 1) fsum += __shfl_xor(fsum, m);
    if (lane == 0) {
        float D = fsum + 1.0f;   // + self loop
        deg[row] = cnt < MAXDEG ? cnt : MAXDEG;
        DsqInv[row] = 1.0f / sqrtf(D);
        Dinv[row] = 1.0f / D;
    }
}

// ---------------------------------------------------------------------------
// Fused MLP: F0 = relu(F@W1+b1)@W2 + b2, Fc = F0.  One block per 8 rows;
// H kept entirely in LDS (no global H buffer).
__global__ void k_mlp(const float* __restrict__ F, const float* __restrict__ W1,
                      const float* __restrict__ b1, const float* __restrict__ W2,
                      const float* __restrict__ b2, float* __restrict__ F0,
                      float* __restrict__ Fc) {
    __shared__ float sF[8][IN_DIM];   // 16 KB
    __shared__ float sH[8][HID];      // 8 KB
    int r0 = blockIdx.x * 8;
    for (int idx = threadIdx.x; idx < 8 * IN_DIM; idx += 256) {
        int r = idx >> 9, c = idx & (IN_DIM - 1);
        sF[r][c] = F[(size_t)(r0 + r) * IN_DIM + c];
    }
    __syncthreads();
    {   // H = relu(F@W1+b1): thread = one hidden col, 8 rows
        int col = threadIdx.x;
        float acc[8];
#pragma unroll
        for (int r = 0; r < 8; r++) acc[r] = 0.f;
        for (int k = 0; k < IN_DIM; k++) {
            float w = W1[(size_t)k * HID + col];
#pragma unroll
            for (int r = 0; r < 8; r++) acc[r] += sF[r][k] * w;
        }
        float b = b1[col];
#pragma unroll
        for (int r = 0; r < 8; r++) sH[r][col] = fmaxf(acc[r] + b, 0.f);
    }
    __syncthreads();
    {   // F0 = H@W2+b2: thread = (out col, 4-row group)
        int col = threadIdx.x & (OUT_DIM - 1);
        int rb = (threadIdx.x >> 7) * 4;
        float acc[4] = {0.f, 0.f, 0.f, 0.f};
        for (int k = 0; k < HID; k++) {
            float w = W2[(size_t)k * OUT_DIM + col];
#pragma unroll
            for (int r = 0; r < 4; r++) acc[r] += sH[rb + r][k] * w;
        }
        float b = b2[col];
#pragma unroll
        for (int r = 0; r < 4; r++) {
            float v = acc[r] + b;
            size_t o = (size_t)(r0 + rb + r) * OUT_DIM + col;
            F0[o] = v;
            Fc[o] = v;
        }
    }
}

// ---------------------------------------------------------------------------
// sq[i] = ||Fc_i||^2 / D_i   (one wave per row)
__global__ void k_sq(const float* __restrict__ Fc, const float* __restrict__ Dinv,
                     float* __restrict__ sq) {
    int wid = threadIdx.x >> 6, lane = threadIdx.x & 63;
    int row = blockIdx.x * 4 + wid;
    float2 f = ((const float2*)Fc)[row * 64 + lane];
    float s = f.x * f.x + f.y * f.y;
#pragma unroll
    for (int m = 1; m < 64; m <<= 1) s += __shfl_xor(s, m);
    if (lane == 0) sq[row] = s * Dinv[row];
}

// ---------------------------------------------------------------------------
// One IRLS propagation step.  One wave per row; per edge: fused
// distance-dot + weighted accumulation.  Emits sq for the next step.
__global__ void k_prop(const float* __restrict__ Fc, const float* __restrict__ F0,
                       const unsigned short* __restrict__ cols, const int* __restrict__ deg,
                       const float* __restrict__ DsqInv, const float* __restrict__ Dinv,
                       const float* __restrict__ sq_in, float* __restrict__ Fc2,
                       float* __restrict__ sq_out) {
    int wid = threadIdx.x >> 6, lane = threadIdx.x & 63;
    int row = blockIdx.x * 4 + wid;
    float dsi = DsqInv[row];
    float sqi = sq_in[row];
    const float2* Fv = (const float2*)Fc;
    float2 fi = Fv[row * 64 + lane];
    float xi0 = fi.x * dsi, xi1 = fi.y * dsi;     // X_i elements (2 per lane)
    float s0 = 0.f, s1 = 0.f, qsum = 0.f;
    int dg = deg[row];
    const unsigned short* cl = cols + (size_t)row * MAXDEG;
    for (int e = 0; e < dg; e++) {
        int j = (int)cl[e];
        float2 fj = Fv[j * 64 + lane];
        float dsj = DsqInv[j];
        float part = xi0 * fj.x + xi1 * fj.y;
#pragma unroll
        for (int m = 1; m < 64; m <<= 1) part += __shfl_xor(part, m);
        float dot = part * dsj;                    // X_i . X_j
        float z = sqi + sq_in[j] - 2.0f * dot;
        z = fmaxf(z, 0.0f);
        float w = fmaxf(1.0f - sqrtf(z) * INV_GAMMA, 0.0f);
        qsum += w;
        float c = w * dsj;
        s0 += c * fj.x;
        s1 += c * fj.y;
    }
    float Q = qsum * Dinv[row] + LAM;
    float invQ = 1.0f / Q;
    float2 f0 = ((const float2*)F0)[row * 64 + lane];
    float o0 = (s0 * dsi + LAM * f0.x) * invQ;
    float o1 = (s1 * dsi + LAM * f0.y) * invQ;
    ((float2*)Fc2)[row * 64 + lane] = make_float2(o0, o1);
    float s = o0 * o0 + o1 * o1;
#pragma unroll
    for (int m = 1; m < 64; m <<= 1) s += __shfl_xor(s, m);
    if (lane == 0) sq_out[row] = s * Dinv[row];
}

extern "C" void kernel_launch(void* const* d_in, const int* in_sizes, int n_in,
                              void* d_out, int out_size, void* d_ws, size_t ws_size,
                              hipStream_t stream) {
    // Resolve inputs by flat size (all six are distinct) — order-proof.
    const float *A = nullptr, *F = nullptr, *W1 = nullptr, *b1 = nullptr,
                *W2 = nullptr, *b2 = nullptr;
    for (int i = 0; i < n_in; i++) {
        switch (in_sizes[i]) {
            case NN * NN:        A  = (const float*)d_in[i]; break;
            case NN * IN_DIM:    F  = (const float*)d_in[i]; break;
            case IN_DIM * HID:   W1 = (const float*)d_in[i]; break;
            case HID:            b1 = (const float*)d_in[i]; break;
            case HID * OUT_DIM:  W2 = (const float*)d_in[i]; break;
            case OUT_DIM:        b2 = (const float*)d_in[i]; break;
            default: break;
        }
    }
    float* out = (float*)d_out;   // reference output dtype is float32

    char* ws = (char*)d_ws;
    float* F0     = (float*)ws; ws += (size_t)NN * OUT_DIM * 4;  // 2 MB
    float* FcA    = (float*)ws; ws += (size_t)NN * OUT_DIM * 4;  // 2 MB
    float* FcB    = (float*)ws; ws += (size_t)NN * OUT_DIM * 4;  // 2 MB
    float* DsqInv = (float*)ws; ws += (size_t)NN * 4;
    float* Dinv   = (float*)ws; ws += (size_t)NN * 4;
    float* sqA    = (float*)ws; ws += (size_t)NN * 4;
    float* sqB    = (float*)ws; ws += (size_t)NN * 4;
    int*   deg    = (int*)ws;   ws += (size_t)NN * 4;
    unsigned short* cols = (unsigned short*)ws; ws += (size_t)NN * MAXDEG * 2; // 1.5 MB

    hipLaunchKernelGGL(k_analyze, dim3(NN / 4), dim3(256), 0, stream, A, cols, deg, DsqInv, Dinv);
    hipLaunchKernelGGL(k_mlp, dim3(NN / 8), dim3(256), 0, stream, F, W1, b1, W2, b2, F0, FcA);
    hipLaunchKernelGGL(k_sq, dim3(NN / 4), dim3(256), 0, stream, FcA, Dinv, sqA);

    float* cur = FcA; float* nxt = FcB;
    float* sqc = sqA; float* sqn = sqB;
    for (int step = 0; step < PROP_STEPS; step++) {
        float* dst = (step == PROP_STEPS - 1) ? out : nxt;   // last step writes d_out (f32)
        hipLaunchKernelGGL(k_prop, dim3(NN / 4), dim3(256), 0, stream,
                           cur, F0, cols, deg, DsqInv, Dinv, sqc, dst, sqn);
        cur = dst;
        float* t = sqc; sqc = sqn; sqn = t;
        if (step < PROP_STEPS - 1) { nxt = (cur == FcA) ? FcB : FcA; }
        if (step == 0) { nxt = FcB; }
        // simple 3-buffer rotation: after step0 cur=FcB(or out), keep alternating
        if (step < PROP_STEPS - 1) nxt = (cur == FcB) ? FcA : FcB;
    }
}

// Round 4
// 551.882 us; speedup vs baseline: 1.2668x; 1.2668x over previous
//
#include <hip/hip_runtime.h>

#define NN 4096
#define IN_DIM 512
#define HID 256
#define OUT_DIM 128
#define MAXDEG 192
#define CHUNK 32
#define INV_GAMMA (1.0f / 6.0f)
#define LAM 0.11111111111111116f   // 1/0.9 - 1
#define PROP_STEPS 10

// ---------------------------------------------------------------------------
// Dense A scan: per-row adjacency list (ushort), degree, D=rowsum+1, 1/D, 1/sqrt(D).
__global__ void k_analyze(const float* __restrict__ A, unsigned short* __restrict__ cols,
                          int* __restrict__ deg, float* __restrict__ DsqInv,
                          float* __restrict__ Dinv) {
    int wid = threadIdx.x >> 6, lane = threadIdx.x & 63;
    int row = blockIdx.x * 4 + wid;
    const float* Ar = A + (size_t)row * NN;
    unsigned short* crow = cols + (size_t)row * MAXDEG;
    int cnt = 0;
    float fsum = 0.f;
    for (int base = 0; base < NN; base += 64) {
        float a = Ar[base + lane];
        fsum += a;
        bool nz = (a != 0.0f);
        unsigned long long m = __ballot(nz);
        if (nz) {
            int off = cnt + __popcll(m & ((1ull << lane) - 1ull));
            if (off < MAXDEG) crow[off] = (unsigned short)(base + lane);
        }
        cnt += __popcll(m);
    }
#pragma unroll
    for (int m = 1; m < 64; m <<= 1) fsum += __shfl_xor(fsum, m);
    if (lane == 0) {
        float D = fsum + 1.0f;
        deg[row] = cnt < MAXDEG ? cnt : MAXDEG;
        DsqInv[row] = 1.0f / sqrtf(D);
        Dinv[row] = 1.0f / D;
    }
}

// ---------------------------------------------------------------------------
// Fused MLP: F0 = relu(F@W1+b1)@W2 + b2; Fc = F0.  8 rows/block, 512 threads.
__global__ __launch_bounds__(512) void k_mlp(const float* __restrict__ F,
                      const float* __restrict__ W1, const float* __restrict__ b1,
                      const float* __restrict__ W2, const float* __restrict__ b2,
                      float* __restrict__ F0, float* __restrict__ Fc) {
    __shared__ __align__(16) float sF[8][IN_DIM];   // 16 KB
    __shared__ __align__(16) float sH[8][260];      // padded (1040B row, 16B-aligned)
    int r0 = blockIdx.x * 8;
    int t = threadIdx.x;
    // stage F rows: 1024 float4 / 512 threads = 2 iters, coalesced
    for (int it = 0; it < 2; ++it) {
        int e = it * 512 + t;
        int r = e >> 7, c4 = e & 127;
        *(float4*)&sF[r][c4 * 4] = *(const float4*)&F[(size_t)(r0 + r) * IN_DIM + c4 * 4];
    }
    __syncthreads();
    {   // layer 1: thread = (col-quad, row); 4 FMA per 16B W1 load
        int cq = t & 63, rg = t >> 6;
        float4 acc = make_float4(0.f, 0.f, 0.f, 0.f);
        for (int k = 0; k < IN_DIM; ++k) {
            float4 w = *(const float4*)&W1[(size_t)k * HID + 4 * cq];
            float f = sF[rg][k];
            acc.x = fmaf(f, w.x, acc.x);
            acc.y = fmaf(f, w.y, acc.y);
            acc.z = fmaf(f, w.z, acc.z);
            acc.w = fmaf(f, w.w, acc.w);
        }
        float4 b = *(const float4*)&b1[4 * cq];
        float4 h;
        h.x = fmaxf(acc.x + b.x, 0.f);
        h.y = fmaxf(acc.y + b.y, 0.f);
        h.z = fmaxf(acc.z + b.z, 0.f);
        h.w = fmaxf(acc.w + b.w, 0.f);
        *(float4*)&sH[rg][4 * cq] = h;
    }
    __syncthreads();
    {   // layer 2: thread = (col, row-half); rows rh and rh+4
        int cd = t & 127, rh = t >> 7;
        float a0 = 0.f, a1 = 0.f;
        for (int k = 0; k < HID; ++k) {
            float w = W2[(size_t)k * OUT_DIM + cd];
            a0 = fmaf(sH[rh][k], w, a0);
            a1 = fmaf(sH[rh + 4][k], w, a1);
        }
        float b = b2[cd];
        a0 += b; a1 += b;
        size_t o0 = (size_t)(r0 + rh) * OUT_DIM + cd;
        size_t o1 = (size_t)(r0 + rh + 4) * OUT_DIM + cd;
        F0[o0] = a0; Fc[o0] = a0;
        F0[o1] = a1; Fc[o1] = a1;
    }
}

// ---------------------------------------------------------------------------
// sq[i] = ||Fc_i||^2 / D_i   (one wave per row)
__global__ void k_sq(const float* __restrict__ Fc, const float* __restrict__ Dinv,
                     float* __restrict__ sq) {
    int wid = threadIdx.x >> 6, lane = threadIdx.x & 63;
    int row = blockIdx.x * 4 + wid;
    float2 f = ((const float2*)Fc)[row * 64 + lane];
    float s = f.x * f.x + f.y * f.y;
#pragma unroll
    for (int m = 1; m < 64; m <<= 1) s += __shfl_xor(s, m);
    if (lane == 0) sq[row] = s * Dinv[row];
}

// ---------------------------------------------------------------------------
// One IRLS step.  Block-per-row, 256 threads.  Per 32-neighbor chunk:
// LDS-stage neighbor rows (coalesced float2), 8-thread/edge dot (3-stage
// shuffle), then LDS SpMM.  High occupancy (~19KB LDS -> 8 blocks/CU).
__global__ __launch_bounds__(256) void k_prop(const float* __restrict__ Fc,
                       const float* __restrict__ F0,
                       const unsigned short* __restrict__ cols, const int* __restrict__ deg,
                       const float* __restrict__ DsqInv, const float* __restrict__ Dinv,
                       const float* __restrict__ sq_in, float* __restrict__ Fc2,
                       float* __restrict__ sq_out) {
    __shared__ __align__(16) float sNb[CHUNK][130];   // stride 130: ~conflict-free
    __shared__ float sX[128], sF0[128];
    __shared__ float sW[CHUNK], sDsj[CHUNK], sSqj[CHUNK];
    __shared__ unsigned short sCols[MAXDEG];
    __shared__ float sQp[32], sHalf[128], sSq2[2], sQred;

    int row = blockIdx.x;
    int t = threadIdx.x;
    float dsi = DsqInv[row];
    float di  = Dinv[row];
    float sqi = sq_in[row];
    int dg = deg[row];
    if (t < 128) {
        float f = Fc[row * 128 + t];
        sX[t] = f * dsi;                       // X_i
        sF0[t] = F0[row * 128 + t];
    }
    for (int e = t; e < dg; e += 256) sCols[e] = cols[(size_t)row * MAXDEG + e];
    __syncthreads();

    int d = t & 127, h = t >> 7;               // SpMM/output mapping
    int so = t >> 3, oc = t & 7;               // dot mapping: slot, octet lane
    float accO = 0.f, qacc = 0.f;

    for (int c0 = 0; c0 < dg; c0 += CHUNK) {
        int nc = dg - c0; if (nc > CHUNK) nc = CHUNK;
        if (t < CHUNK) {
            if (t < nc) { int j = sCols[c0 + t]; sDsj[t] = DsqInv[j]; sSqj[t] = sq_in[j]; }
            else        { sDsj[t] = 0.f; sSqj[t] = 0.f; }
        }
        // stage 32 neighbor rows: 2048 float2 / 256 thr = 8 iters, coalesced
#pragma unroll
        for (int it = 0; it < (CHUNK * 64) / 256; ++it) {
            int e = it * 256 + t;
            int s = e >> 6, d2 = e & 63;
            float2 v = make_float2(0.f, 0.f);
            if (s < nc) { int j = sCols[c0 + s]; v = ((const float2*)Fc)[j * 64 + d2]; }
            *(float2*)&sNb[s][2 * d2] = v;
        }
        __syncthreads();
        // dots: 8 threads per slot, 16 dims each, 3-stage reduce
        {
            float part = 0.f;
#pragma unroll
            for (int i = 0; i < 16; ++i) {
                int dd = oc + 8 * i;
                part = fmaf(sX[dd], sNb[so][dd], part);
            }
            part += __shfl_xor(part, 1);
            part += __shfl_xor(part, 2);
            part += __shfl_xor(part, 4);
            float w = 0.f;
            if (so < nc) {
                float dot = part * sDsj[so];
                float z = fmaxf(sqi + sSqj[so] - 2.f * dot, 0.f);
                w = fmaxf(1.f - sqrtf(z) * INV_GAMMA, 0.f);
            }
            if (oc == 0) { sW[so] = w * sDsj[so]; qacc += w; }
        }
        __syncthreads();
        // SpMM: thread (d, h) accumulates its half of the slots
#pragma unroll
        for (int s2 = 0; s2 < CHUNK / 2; ++s2) {
            int s = h * (CHUNK / 2) + s2;
            accO = fmaf(sW[s], sNb[s][d], accO);
        }
        __syncthreads();
    }
    // qsum reduce (32 partials in wave 0)
    if (oc == 0) sQp[so] = qacc;
    __syncthreads();
    if (t < 32) {
        float v = sQp[t];
#pragma unroll
        for (int m = 1; m < 32; m <<= 1) v += __shfl_xor(v, m);
        if (t == 0) sQred = v;
    }
    if (h == 1) sHalf[d] = accO;
    __syncthreads();
    float invQ = 1.f / (sQred * di + LAM);
    if (h == 0) {
        float o = accO + sHalf[d];
        o = (o * dsi + LAM * sF0[d]) * invQ;
        Fc2[row * 128 + d] = o;
        float ss = o * o;
#pragma unroll
        for (int m = 1; m < 64; m <<= 1) ss += __shfl_xor(ss, m);
        if ((t & 63) == 0) sSq2[t >> 6] = ss;
    }
    __syncthreads();
    if (t == 0) sq_out[row] = (sSq2[0] + sSq2[1]) * di;
}

extern "C" void kernel_launch(void* const* d_in, const int* in_sizes, int n_in,
                              void* d_out, int out_size, void* d_ws, size_t ws_size,
                              hipStream_t stream) {
    const float *A = nullptr, *F = nullptr, *W1 = nullptr, *b1 = nullptr,
                *W2 = nullptr, *b2 = nullptr;
    for (int i = 0; i < n_in; i++) {
        switch (in_sizes[i]) {
            case NN * NN:        A  = (const float*)d_in[i]; break;
            case NN * IN_DIM:    F  = (const float*)d_in[i]; break;
            case IN_DIM * HID:   W1 = (const float*)d_in[i]; break;
            case HID:            b1 = (const float*)d_in[i]; break;
            case HID * OUT_DIM:  W2 = (const float*)d_in[i]; break;
            case OUT_DIM:        b2 = (const float*)d_in[i]; break;
            default: break;
        }
    }
    float* out = (float*)d_out;

    char* ws = (char*)d_ws;
    float* F0     = (float*)ws; ws += (size_t)NN * OUT_DIM * 4;
    float* FcA    = (float*)ws; ws += (size_t)NN * OUT_DIM * 4;
    float* FcB    = (float*)ws; ws += (size_t)NN * OUT_DIM * 4;
    float* DsqInv = (float*)ws; ws += (size_t)NN * 4;
    float* Dinv   = (float*)ws; ws += (size_t)NN * 4;
    float* sqA    = (float*)ws; ws += (size_t)NN * 4;
    float* sqB    = (float*)ws; ws += (size_t)NN * 4;
    int*   deg    = (int*)ws;   ws += (size_t)NN * 4;
    unsigned short* cols = (unsigned short*)ws; ws += (size_t)NN * MAXDEG * 2;

    hipLaunchKernelGGL(k_analyze, dim3(NN / 4), dim3(256), 0, stream, A, cols, deg, DsqInv, Dinv);
    hipLaunchKernelGGL(k_mlp, dim3(NN / 8), dim3(512), 0, stream, F, W1, b1, W2, b2, F0, FcA);
    hipLaunchKernelGGL(k_sq, dim3(NN / 4), dim3(256), 0, stream, FcA, Dinv, sqA);

    float* cur = FcA;
    float* sqc = sqA; float* sqn = sqB;
    for (int step = 0; step < PROP_STEPS; step++) {
        float* dst = (step == PROP_STEPS - 1) ? out : ((step & 1) ? FcA : FcB);
        hipLaunchKernelGGL(k_prop, dim3(NN), dim3(256), 0, stream,
                           cur, F0, cols, deg, DsqInv, Dinv, sqc, dst, sqn);
        cur = dst;
        float* tmp = sqc; sqc = sqn; sqn = tmp;
    }
}

// Round 5
// 537.654 us; speedup vs baseline: 1.3004x; 1.0265x over previous
//
#include <hip/hip_runtime.h>

#define NN 4096
#define IN_DIM 512
#define HID 256
#define OUT_DIM 128
#define MAXDEG 192
#define INV_GAMMA (1.0f / 6.0f)
#define LAM 0.11111111111111116f   // 1/0.9 - 1
#define PROP_STEPS 10

// ---------------------------------------------------------------------------
// Dense A scan (float4): per-row adjacency list, degree, D=rowsum+1, 1/D, 1/sqrt(D).
__global__ void k_analyze(const float* __restrict__ A, unsigned short* __restrict__ cols,
                          int* __restrict__ deg, float* __restrict__ DsqInv,
                          float* __restrict__ Dinv) {
    int wid = threadIdx.x >> 6, lane = threadIdx.x & 63;
    int row = blockIdx.x * 4 + wid;
    const float4* Ar = (const float4*)(A + (size_t)row * NN);
    unsigned short* crow = cols + (size_t)row * MAXDEG;
    int cnt = 0;
    float fsum = 0.f;
    for (int it = 0; it < NN / 256; ++it) {
        float4 v = Ar[it * 64 + lane];
        fsum += (v.x + v.y) + (v.z + v.w);
        int colbase = (it * 64 + lane) * 4;
        float comp[4] = {v.x, v.y, v.z, v.w};
#pragma unroll
        for (int c = 0; c < 4; ++c) {
            bool nz = (comp[c] != 0.f);
            unsigned long long m = __ballot(nz);
            if (nz) {
                int off = cnt + __popcll(m & ((1ull << lane) - 1ull));
                if (off < MAXDEG) crow[off] = (unsigned short)(colbase + c);
            }
            cnt += __popcll(m);
        }
    }
#pragma unroll
    for (int m = 1; m < 64; m <<= 1) fsum += __shfl_xor(fsum, m);
    if (lane == 0) {
        float D = fsum + 1.0f;
        deg[row] = cnt < MAXDEG ? cnt : MAXDEG;
        DsqInv[row] = 1.0f / sqrtf(D);
        Dinv[row] = 1.0f / D;
    }
}

// ---------------------------------------------------------------------------
// Fused MLP, LDS-tiled: F0 = relu(F@W1+b1)@W2 + b2; also X0 = F0 / sqrt(D).
// 256 blocks x 16 rows, 256 threads.  LDS: sF 32KB + sW 32KB + sH 16KB = 80KB.
__global__ __launch_bounds__(256) void k_mlp(const float* __restrict__ F,
                      const float* __restrict__ W1, const float* __restrict__ b1,
                      const float* __restrict__ W2, const float* __restrict__ b2,
                      const float* __restrict__ DsqInv,
                      float* __restrict__ F0, float* __restrict__ X0) {
    __shared__ __align__(16) float sF[16 * IN_DIM];
    __shared__ __align__(16) float sW[32 * 256];
    __shared__ __align__(16) float sH[16 * HID];
    int r0 = blockIdx.x * 16;
    int t = threadIdx.x;
    // stage F rows: 2048 float4 / 256 thr = 8 each
#pragma unroll
    for (int i = 0; i < 8; ++i) {
        int idx = i * 256 + t;
        int r = idx >> 7, q = idx & 127;
        *(float4*)&sF[r * IN_DIM + 4 * q] = *(const float4*)&F[(size_t)(r0 + r) * IN_DIM + 4 * q];
    }
    {   // ---- layer 1: thread = (4 cols, 4 rows) ----
        int cq = t & 63, rg = t >> 6;          // wave-uniform rg -> sF reads broadcast
        float4 acc[4];
#pragma unroll
        for (int i = 0; i < 4; ++i) acc[i] = make_float4(0.f, 0.f, 0.f, 0.f);
        for (int kt = 0; kt < IN_DIM / 32; ++kt) {
            __syncthreads();
            // stage W1 tile [32][256]: 2048 float4 / 256 thr = 8 each
#pragma unroll
            for (int i = 0; i < 8; ++i) {
                int idx = i * 256 + t;
                int kr = idx >> 6, q = idx & 63;
                *(float4*)&sW[kr * 256 + 4 * q] =
                    *(const float4*)&W1[(size_t)(kt * 32 + kr) * HID + 4 * q];
            }
            __syncthreads();
#pragma unroll
            for (int kk = 0; kk < 32; ++kk) {
                int k = kt * 32 + kk;
                float4 w = *(float4*)&sW[kk * 256 + 4 * cq];
#pragma unroll
                for (int i = 0; i < 4; ++i) {
                    float f = sF[(rg * 4 + i) * IN_DIM + k];
                    acc[i].x = fmaf(f, w.x, acc[i].x);
                    acc[i].y = fmaf(f, w.y, acc[i].y);
                    acc[i].z = fmaf(f, w.z, acc[i].z);
                    acc[i].w = fmaf(f, w.w, acc[i].w);
                }
            }
        }
        float4 b = *(const float4*)&b1[4 * cq];
#pragma unroll
        for (int i = 0; i < 4; ++i) {
            float4 h;
            h.x = fmaxf(acc[i].x + b.x, 0.f);
            h.y = fmaxf(acc[i].y + b.y, 0.f);
            h.z = fmaxf(acc[i].z + b.z, 0.f);
            h.w = fmaxf(acc[i].w + b.w, 0.f);
            *(float4*)&sH[(rg * 4 + i) * HID + 4 * cq] = h;
        }
    }
    {   // ---- layer 2: thread = (1 col, 8 rows) ----
        int c = t & 127, rg2 = t >> 7;
        float acc2[8];
#pragma unroll
        for (int r = 0; r < 8; ++r) acc2[r] = 0.f;
        for (int kt = 0; kt < HID / 32; ++kt) {
            __syncthreads();
            // stage W2 tile [32][128]: 1024 float4 / 256 thr = 4 each
#pragma unroll
            for (int i = 0; i < 4; ++i) {
                int idx = i * 256 + t;
                int kr = idx >> 5, q = idx & 31;
                *(float4*)&sW[kr * 128 + 4 * q] =
                    *(const float4*)&W2[(size_t)(kt * 32 + kr) * OUT_DIM + 4 * q];
            }
            __syncthreads();
#pragma unroll
            for (int kk = 0; kk < 32; ++kk) {
                int k = kt * 32 + kk;
                float w = sW[kk * 128 + c];
#pragma unroll
                for (int r = 0; r < 8; ++r)
                    acc2[r] = fmaf(sH[(rg2 * 8 + r) * HID + k], w, acc2[r]);
            }
        }
        float b = b2[c];
#pragma unroll
        for (int r = 0; r < 8; ++r) {
            int row = r0 + rg2 * 8 + r;
            float v = acc2[r] + b;
            F0[(size_t)row * OUT_DIM + c] = v;
            X0[(size_t)row * OUT_DIM + c] = v * DsqInv[row];
        }
    }
}

// ---------------------------------------------------------------------------
// sq[i] = ||X_i||^2  (one wave per row)
__global__ void k_sq0(const float* __restrict__ X, float* __restrict__ sq) {
    int wid = threadIdx.x >> 6, lane = threadIdx.x & 63;
    int row = blockIdx.x * 4 + wid;
    float2 x = ((const float2*)X)[row * 64 + lane];
    float s = x.x * x.x + x.y * x.y;
#pragma unroll
    for (int m = 1; m < 64; m <<= 1) s += __shfl_xor(s, m);
    if (lane == 0) sq[row] = s;
}

// ---------------------------------------------------------------------------
// Edge weights: wave per row, 8-lane group per edge, X_i slice in registers.
// w_e = max(1 - sqrt(max(sqi+sqj-2*Xi.Xj,0))/gamma, 0)
__global__ __launch_bounds__(256) void k_edge(const float* __restrict__ X,
                       const float* __restrict__ sq,
                       const unsigned short* __restrict__ cols,
                       const int* __restrict__ deg, float* __restrict__ wbuf) {
    int wid = threadIdx.x >> 6, lane = threadIdx.x & 63;
    int row = blockIdx.x * 4 + wid;
    int g = lane >> 3, oc = lane & 7;
    int dg = deg[row];
    float sqi = sq[row];
    const float4* Xi4 = (const float4*)(X + (size_t)row * 128 + oc * 16);
    float4 xi0 = Xi4[0], xi1 = Xi4[1], xi2 = Xi4[2], xi3 = Xi4[3];
    const unsigned short* cl = cols + (size_t)row * MAXDEG;
    float* wr = wbuf + (size_t)row * MAXDEG;
    for (int c0 = 0; c0 < dg; c0 += 8) {
        int e = c0 + g;
        bool act = (e < dg);
        int j = act ? (int)cl[e] : row;
        const float4* Xj4 = (const float4*)(X + (size_t)j * 128 + oc * 16);
        float4 a = Xj4[0], b = Xj4[1], c = Xj4[2], d = Xj4[3];
        float p = 0.f;
        p = fmaf(xi0.x, a.x, p); p = fmaf(xi0.y, a.y, p);
        p = fmaf(xi0.z, a.z, p); p = fmaf(xi0.w, a.w, p);
        p = fmaf(xi1.x, b.x, p); p = fmaf(xi1.y, b.y, p);
        p = fmaf(xi1.z, b.z, p); p = fmaf(xi1.w, b.w, p);
        p = fmaf(xi2.x, c.x, p); p = fmaf(xi2.y, c.y, p);
        p = fmaf(xi2.z, c.z, p); p = fmaf(xi2.w, c.w, p);
        p = fmaf(xi3.x, d.x, p); p = fmaf(xi3.y, d.y, p);
        p = fmaf(xi3.z, d.z, p); p = fmaf(xi3.w, d.w, p);
        p += __shfl_xor(p, 1);
        p += __shfl_xor(p, 2);
        p += __shfl_xor(p, 4);
        if (act && oc == 0) {
            float z = fmaxf(sqi + sq[j] - 2.f * p, 0.f);
            wr[e] = fmaxf(1.f - sqrtf(z) * INV_GAMMA, 0.f);
        }
    }
}

// ---------------------------------------------------------------------------
// SpMM + IRLS update: wave per row.  w is lane-uniform -> qsum needs no reduce.
// Writes either X_next+sq_next (intermediate) or Fc (final step, to d_out).
__global__ __launch_bounds__(256) void k_spmm(const float* __restrict__ X,
                       const float* __restrict__ F0,
                       const unsigned short* __restrict__ cols,
                       const int* __restrict__ deg, const float* __restrict__ wbuf,
                       const float* __restrict__ DsqInv, const float* __restrict__ Dinv,
                       float* __restrict__ Xout, float* __restrict__ sq_out,
                       float* __restrict__ FcOut, int final_step) {
    int wid = threadIdx.x >> 6, lane = threadIdx.x & 63;
    int row = blockIdx.x * 4 + wid;
    int dg = deg[row];
    float dsi = DsqInv[row], di = Dinv[row];
    const float2* Xv = (const float2*)X;
    const unsigned short* cl = cols + (size_t)row * MAXDEG;
    const float* wr = wbuf + (size_t)row * MAXDEG;
    float s0 = 0.f, s1 = 0.f, qs = 0.f;
    for (int e = 0; e < dg; ++e) {
        int j = (int)cl[e];
        float w = wr[e];
        float2 xj = Xv[j * 64 + lane];
        s0 = fmaf(w, xj.x, s0);
        s1 = fmaf(w, xj.y, s1);
        qs += w;
    }
    float invQ = 1.f / (qs * di + LAM);
    float2 f0 = ((const float2*)F0)[row * 64 + lane];
    float o0 = (dsi * s0 + LAM * f0.x) * invQ;
    float o1 = (dsi * s1 + LAM * f0.y) * invQ;
    if (final_step) {
        ((float2*)FcOut)[row * 64 + lane] = make_float2(o0, o1);
    } else {
        float x0 = o0 * dsi, x1 = o1 * dsi;
        ((float2*)Xout)[row * 64 + lane] = make_float2(x0, x1);
        float ss = x0 * x0 + x1 * x1;
#pragma unroll
        for (int m = 1; m < 64; m <<= 1) ss += __shfl_xor(ss, m);
        if (lane == 0) sq_out[row] = ss;
    }
}

extern "C" void kernel_launch(void* const* d_in, const int* in_sizes, int n_in,
                              void* d_out, int out_size, void* d_ws, size_t ws_size,
                              hipStream_t stream) {
    const float *A = nullptr, *F = nullptr, *W1 = nullptr, *b1 = nullptr,
                *W2 = nullptr, *b2 = nullptr;
    for (int i = 0; i < n_in; i++) {
        switch (in_sizes[i]) {
            case NN * NN:        A  = (const float*)d_in[i]; break;
            case NN * IN_DIM:    F  = (const float*)d_in[i]; break;
            case IN_DIM * HID:   W1 = (const float*)d_in[i]; break;
            case HID:            b1 = (const float*)d_in[i]; break;
            case HID * OUT_DIM:  W2 = (const float*)d_in[i]; break;
            case OUT_DIM:        b2 = (const float*)d_in[i]; break;
            default: break;
        }
    }
    float* out = (float*)d_out;

    char* ws = (char*)d_ws;
    float* F0     = (float*)ws; ws += (size_t)NN * OUT_DIM * 4;   // 2 MB
    float* XA     = (float*)ws; ws += (size_t)NN * OUT_DIM * 4;   // 2 MB
    float* XB     = (float*)ws; ws += (size_t)NN * OUT_DIM * 4;   // 2 MB
    float* wbuf   = (float*)ws; ws += (size_t)NN * MAXDEG * 4;    // 3 MB
    float* DsqInv = (float*)ws; ws += (size_t)NN * 4;
    float* Dinv   = (float*)ws; ws += (size_t)NN * 4;
    float* sqA    = (float*)ws; ws += (size_t)NN * 4;
    float* sqB    = (float*)ws; ws += (size_t)NN * 4;
    int*   deg    = (int*)ws;   ws += (size_t)NN * 4;
    unsigned short* cols = (unsigned short*)ws; ws += (size_t)NN * MAXDEG * 2; // 1.5 MB

    hipLaunchKernelGGL(k_analyze, dim3(NN / 4), dim3(256), 0, stream, A, cols, deg, DsqInv, Dinv);
    hipLaunchKernelGGL(k_mlp, dim3(NN / 16), dim3(256), 0, stream,
                       F, W1, b1, W2, b2, DsqInv, F0, XA);
    hipLaunchKernelGGL(k_sq0, dim3(NN / 4), dim3(256), 0, stream, XA, sqA);

    float* Xc = XA; float* Xn = XB;
    float* sqc = sqA; float* sqn = sqB;
    for (int step = 0; step < PROP_STEPS; step++) {
        int fin = (step == PROP_STEPS - 1) ? 1 : 0;
        hipLaunchKernelGGL(k_edge, dim3(NN / 4), dim3(256), 0, stream,
                           Xc, sqc, cols, deg, wbuf);
        hipLaunchKernelGGL(k_spmm, dim3(NN / 4), dim3(256), 0, stream,
                           Xc, F0, cols, deg, wbuf, DsqInv, Dinv, Xn, sqn, out, fin);
        float* t1 = Xc; Xc = Xn; Xn = t1;
        float* t2 = sqc; sqc = sqn; sqn = t2;
    }
}

// Round 6
// 289.752 us; speedup vs baseline: 2.4129x; 1.8556x over previous
//
#include <hip/hip_runtime.h>

#define NN 4096
#define IN_DIM 512
#define HID 256
#define OUT_DIM 128
#define MAXDEG 192
#define INV_GAMMA (1.0f / 6.0f)
#define LAM 0.11111111111111116f   // 1/0.9 - 1
#define PROP_STEPS 10

// ---------------------------------------------------------------------------
// Dense A scan (float4): per-row adjacency list, degree, D=rowsum+1, 1/D, 1/sqrt(D).
__global__ void k_analyze(const float* __restrict__ A, unsigned short* __restrict__ cols,
                          int* __restrict__ deg, float* __restrict__ DsqInv,
                          float* __restrict__ Dinv) {
    int wid = threadIdx.x >> 6, lane = threadIdx.x & 63;
    int row = blockIdx.x * 4 + wid;
    const float4* Ar = (const float4*)(A + (size_t)row * NN);
    unsigned short* crow = cols + (size_t)row * MAXDEG;
    int cnt = 0;
    float fsum = 0.f;
    for (int it = 0; it < NN / 256; ++it) {
        float4 v = Ar[it * 64 + lane];
        fsum += (v.x + v.y) + (v.z + v.w);
        int colbase = (it * 64 + lane) * 4;
        float comp[4] = {v.x, v.y, v.z, v.w};
#pragma unroll
        for (int c = 0; c < 4; ++c) {
            bool nz = (comp[c] != 0.f);
            unsigned long long m = __ballot(nz);
            if (nz) {
                int off = cnt + __popcll(m & ((1ull << lane) - 1ull));
                if (off < MAXDEG) crow[off] = (unsigned short)(colbase + c);
            }
            cnt += __popcll(m);
        }
    }
#pragma unroll
    for (int m = 1; m < 64; m <<= 1) fsum += __shfl_xor(fsum, m);
    if (lane == 0) {
        float D = fsum + 1.0f;
        deg[row] = cnt < MAXDEG ? cnt : MAXDEG;
        DsqInv[row] = 1.0f / sqrtf(D);
        Dinv[row] = 1.0f / D;
    }
}

// ---------------------------------------------------------------------------
// Fused MLP: F0 = relu(F@W1+b1)@W2 + b2; X0 = F0/sqrt(D).
// 512 blocks x 8 rows, 256 threads.  LDS 56KB -> 2 blocks/CU.
__global__ __launch_bounds__(256) void k_mlp(const float* __restrict__ F,
                      const float* __restrict__ W1, const float* __restrict__ b1,
                      const float* __restrict__ W2, const float* __restrict__ b2,
                      const float* __restrict__ DsqInv,
                      float* __restrict__ F0, float* __restrict__ X0) {
    __shared__ __align__(16) float sF[8 * IN_DIM];   // 16 KB
    __shared__ __align__(16) float sW[32 * 256];     // 32 KB
    __shared__ __align__(16) float sH[8 * HID];      // 8 KB
    int r0 = blockIdx.x * 8;
    int t = threadIdx.x;
    // stage 8 F rows: 1024 float4 / 256 thr
#pragma unroll
    for (int i = 0; i < 4; ++i) {
        int idx = i * 256 + t;
        int r = idx >> 7, q = idx & 127;
        *(float4*)&sF[r * IN_DIM + 4 * q] = *(const float4*)&F[(size_t)(r0 + r) * IN_DIM + 4 * q];
    }
    {   // layer 1: thread = (4 cols, 2 rows)
        int cq = t & 63, rg = t >> 6;
        float4 accA = make_float4(0.f, 0.f, 0.f, 0.f);
        float4 accB = make_float4(0.f, 0.f, 0.f, 0.f);
        for (int kt = 0; kt < IN_DIM / 32; ++kt) {
            __syncthreads();
#pragma unroll
            for (int i = 0; i < 8; ++i) {     // stage W1 tile [32][256]
                int idx = i * 256 + t;
                int kr = idx >> 6, q = idx & 63;
                *(float4*)&sW[kr * 256 + 4 * q] =
                    *(const float4*)&W1[(size_t)(kt * 32 + kr) * HID + 4 * q];
            }
            __syncthreads();
#pragma unroll
            for (int kk = 0; kk < 32; ++kk) {
                int k = kt * 32 + kk;
                float4 w = *(float4*)&sW[kk * 256 + 4 * cq];
                float fa = sF[(2 * rg) * IN_DIM + k];
                float fb = sF[(2 * rg + 1) * IN_DIM + k];
                accA.x = fmaf(fa, w.x, accA.x); accA.y = fmaf(fa, w.y, accA.y);
                accA.z = fmaf(fa, w.z, accA.z); accA.w = fmaf(fa, w.w, accA.w);
                accB.x = fmaf(fb, w.x, accB.x); accB.y = fmaf(fb, w.y, accB.y);
                accB.z = fmaf(fb, w.z, accB.z); accB.w = fmaf(fb, w.w, accB.w);
            }
        }
        float4 b = *(const float4*)&b1[4 * cq];
        float4 ha, hb;
        ha.x = fmaxf(accA.x + b.x, 0.f); ha.y = fmaxf(accA.y + b.y, 0.f);
        ha.z = fmaxf(accA.z + b.z, 0.f); ha.w = fmaxf(accA.w + b.w, 0.f);
        hb.x = fmaxf(accB.x + b.x, 0.f); hb.y = fmaxf(accB.y + b.y, 0.f);
        hb.z = fmaxf(accB.z + b.z, 0.f); hb.w = fmaxf(accB.w + b.w, 0.f);
        *(float4*)&sH[(2 * rg) * HID + 4 * cq] = ha;
        *(float4*)&sH[(2 * rg + 1) * HID + 4 * cq] = hb;
    }
    {   // layer 2: thread = (1 col, 4 rows)
        int c = t & 127, half = t >> 7;
        float acc2[4] = {0.f, 0.f, 0.f, 0.f};
        for (int kt = 0; kt < HID / 32; ++kt) {
            __syncthreads();
#pragma unroll
            for (int i = 0; i < 4; ++i) {     // stage W2 tile [32][128]
                int idx = i * 256 + t;
                int kr = idx >> 5, q = idx & 31;
                *(float4*)&sW[kr * 128 + 4 * q] =
                    *(const float4*)&W2[(size_t)(kt * 32 + kr) * OUT_DIM + 4 * q];
            }
            __syncthreads();
#pragma unroll
            for (int kk = 0; kk < 32; ++kk) {
                int k = kt * 32 + kk;
                float w = sW[kk * 128 + c];
#pragma unroll
                for (int r = 0; r < 4; ++r)
                    acc2[r] = fmaf(sH[(half * 4 + r) * HID + k], w, acc2[r]);
            }
        }
        float b = b2[c];
#pragma unroll
        for (int r = 0; r < 4; ++r) {
            int row = r0 + half * 4 + r;
            float v = acc2[r] + b;
            F0[(size_t)row * OUT_DIM + c] = v;
            X0[(size_t)row * OUT_DIM + c] = v * DsqInv[row];
        }
    }
}

// ---------------------------------------------------------------------------
// Fully fused IRLS step: wave per row, 8-lane group per edge.  Per chunk of 8
// edges: load X_j slice (4 float4/lane), compute dot AND ||X_j||^2 in-register
// (3+3 group shuffles), weight w, accumulate acc += w*X_j.  No sq buffers,
// no wbuf, X gathered exactly once per step.
__global__ __launch_bounds__(256) void k_prop(const float* __restrict__ X,
                       const float* __restrict__ F0,
                       const unsigned short* __restrict__ cols, const int* __restrict__ deg,
                       const float* __restrict__ DsqInv, const float* __restrict__ Dinv,
                       float* __restrict__ Xout, float* __restrict__ FcOut, int final_step) {
    __shared__ unsigned short sCols[4][MAXDEG];
    int wid = threadIdx.x >> 6, lane = threadIdx.x & 63;
    int row = blockIdx.x * 4 + wid;
    int g = lane >> 3, oc = lane & 7;
    int dg = deg[row];
    float dsi = DsqInv[row], di = Dinv[row];
    for (int e = lane; e < dg; e += 64) sCols[wid][e] = cols[(size_t)row * MAXDEG + e];
    // X_i slice: 16 floats per lane (same across the 8 groups)
    const float4* Xi4 = (const float4*)(X + (size_t)row * 128 + oc * 16);
    float4 xi0 = Xi4[0], xi1 = Xi4[1], xi2 = Xi4[2], xi3 = Xi4[3];
    // sqi = ||X_i||^2 (intra-group reduce)
    float sqi;
    {
        float s = 0.f;
        s = fmaf(xi0.x, xi0.x, s); s = fmaf(xi0.y, xi0.y, s);
        s = fmaf(xi0.z, xi0.z, s); s = fmaf(xi0.w, xi0.w, s);
        s = fmaf(xi1.x, xi1.x, s); s = fmaf(xi1.y, xi1.y, s);
        s = fmaf(xi1.z, xi1.z, s); s = fmaf(xi1.w, xi1.w, s);
        s = fmaf(xi2.x, xi2.x, s); s = fmaf(xi2.y, xi2.y, s);
        s = fmaf(xi2.z, xi2.z, s); s = fmaf(xi2.w, xi2.w, s);
        s = fmaf(xi3.x, xi3.x, s); s = fmaf(xi3.y, xi3.y, s);
        s = fmaf(xi3.z, xi3.z, s); s = fmaf(xi3.w, xi3.w, s);
        s += __shfl_xor(s, 1); s += __shfl_xor(s, 2); s += __shfl_xor(s, 4);
        sqi = s;
    }
    float acc[16];
#pragma unroll
    for (int i = 0; i < 16; ++i) acc[i] = 0.f;
    float qacc = 0.f;
    int nch = (dg + 7) >> 3;
    for (int ch = 0; ch < nch; ++ch) {
        int e = ch * 8 + g;
        bool act = (e < dg);
        int ec = act ? e : (dg - 1);
        int j = (int)sCols[wid][ec];
        const float4* Xj4 = (const float4*)(X + (size_t)j * 128 + oc * 16);
        float4 a = Xj4[0], b = Xj4[1], c = Xj4[2], d = Xj4[3];
        float p = 0.f, sj = 0.f;
        p = fmaf(xi0.x, a.x, p); sj = fmaf(a.x, a.x, sj);
        p = fmaf(xi0.y, a.y, p); sj = fmaf(a.y, a.y, sj);
        p = fmaf(xi0.z, a.z, p); sj = fmaf(a.z, a.z, sj);
        p = fmaf(xi0.w, a.w, p); sj = fmaf(a.w, a.w, sj);
        p = fmaf(xi1.x, b.x, p); sj = fmaf(b.x, b.x, sj);
        p = fmaf(xi1.y, b.y, p); sj = fmaf(b.y, b.y, sj);
        p = fmaf(xi1.z, b.z, p); sj = fmaf(b.z, b.z, sj);
        p = fmaf(xi1.w, b.w, p); sj = fmaf(b.w, b.w, sj);
        p = fmaf(xi2.x, c.x, p); sj = fmaf(c.x, c.x, sj);
        p = fmaf(xi2.y, c.y, p); sj = fmaf(c.y, c.y, sj);
        p = fmaf(xi2.z, c.z, p); sj = fmaf(c.z, c.z, sj);
        p = fmaf(xi2.w, c.w, p); sj = fmaf(c.w, c.w, sj);
        p = fmaf(xi3.x, d.x, p); sj = fmaf(d.x, d.x, sj);
        p = fmaf(xi3.y, d.y, p); sj = fmaf(d.y, d.y, sj);
        p = fmaf(xi3.z, d.z, p); sj = fmaf(d.z, d.z, sj);
        p = fmaf(xi3.w, d.w, p); sj = fmaf(d.w, d.w, sj);
        p += __shfl_xor(p, 1); p += __shfl_xor(p, 2); p += __shfl_xor(p, 4);
        sj += __shfl_xor(sj, 1); sj += __shfl_xor(sj, 2); sj += __shfl_xor(sj, 4);
        float z = fmaxf(sqi + sj - 2.f * p, 0.f);
        float w = fmaxf(1.f - sqrtf(z) * INV_GAMMA, 0.f);
        w = act ? w : 0.f;
        qacc += w;
        acc[0]  = fmaf(w, a.x, acc[0]);  acc[1]  = fmaf(w, a.y, acc[1]);
        acc[2]  = fmaf(w, a.z, acc[2]);  acc[3]  = fmaf(w, a.w, acc[3]);
        acc[4]  = fmaf(w, b.x, acc[4]);  acc[5]  = fmaf(w, b.y, acc[5]);
        acc[6]  = fmaf(w, b.z, acc[6]);  acc[7]  = fmaf(w, b.w, acc[7]);
        acc[8]  = fmaf(w, c.x, acc[8]);  acc[9]  = fmaf(w, c.y, acc[9]);
        acc[10] = fmaf(w, c.z, acc[10]); acc[11] = fmaf(w, c.w, acc[11]);
        acc[12] = fmaf(w, d.x, acc[12]); acc[13] = fmaf(w, d.y, acc[13]);
        acc[14] = fmaf(w, d.z, acc[14]); acc[15] = fmaf(w, d.w, acc[15]);
    }
    // reduce across the 8 groups (masks 8,16,32)
#pragma unroll
    for (int m = 8; m <= 32; m <<= 1) {
        qacc += __shfl_xor(qacc, m);
#pragma unroll
        for (int i = 0; i < 16; ++i) acc[i] += __shfl_xor(acc[i], m);
    }
    float invQ = 1.f / (qacc * di + LAM);
    if (g == 0) {   // lanes 0..7 write the 128-dim row
        const float4* F04 = (const float4*)(F0 + (size_t)row * 128 + oc * 16);
        float* dstF = (float*)(FcOut + (size_t)row * 128 + oc * 16);
        float* dstX = (float*)(Xout + (size_t)row * 128 + oc * 16);
#pragma unroll
        for (int q = 0; q < 4; ++q) {
            float4 f0 = F04[q];
            float4 o;
            o.x = (dsi * acc[4 * q + 0] + LAM * f0.x) * invQ;
            o.y = (dsi * acc[4 * q + 1] + LAM * f0.y) * invQ;
            o.z = (dsi * acc[4 * q + 2] + LAM * f0.z) * invQ;
            o.w = (dsi * acc[4 * q + 3] + LAM * f0.w) * invQ;
            if (final_step) {
                *(float4*)&dstF[4 * q] = o;
            } else {
                float4 xo;
                xo.x = o.x * dsi; xo.y = o.y * dsi; xo.z = o.z * dsi; xo.w = o.w * dsi;
                *(float4*)&dstX[4 * q] = xo;
            }
        }
    }
}

extern "C" void kernel_launch(void* const* d_in, const int* in_sizes, int n_in,
                              void* d_out, int out_size, void* d_ws, size_t ws_size,
                              hipStream_t stream) {
    const float *A = nullptr, *F = nullptr, *W1 = nullptr, *b1 = nullptr,
                *W2 = nullptr, *b2 = nullptr;
    for (int i = 0; i < n_in; i++) {
        switch (in_sizes[i]) {
            case NN * NN:        A  = (const float*)d_in[i]; break;
            case NN * IN_DIM:    F  = (const float*)d_in[i]; break;
            case IN_DIM * HID:   W1 = (const float*)d_in[i]; break;
            case HID:            b1 = (const float*)d_in[i]; break;
            case HID * OUT_DIM:  W2 = (const float*)d_in[i]; break;
            case OUT_DIM:        b2 = (const float*)d_in[i]; break;
            default: break;
        }
    }
    float* out = (float*)d_out;

    char* ws = (char*)d_ws;
    float* F0     = (float*)ws; ws += (size_t)NN * OUT_DIM * 4;   // 2 MB
    float* XA     = (float*)ws; ws += (size_t)NN * OUT_DIM * 4;   // 2 MB
    float* XB     = (float*)ws; ws += (size_t)NN * OUT_DIM * 4;   // 2 MB
    float* DsqInv = (float*)ws; ws += (size_t)NN * 4;
    float* Dinv   = (float*)ws; ws += (size_t)NN * 4;
    int*   deg    = (int*)ws;   ws += (size_t)NN * 4;
    unsigned short* cols = (unsigned short*)ws; ws += (size_t)NN * MAXDEG * 2; // 1.5 MB

    hipLaunchKernelGGL(k_analyze, dim3(NN / 4), dim3(256), 0, stream, A, cols, deg, DsqInv, Dinv);
    hipLaunchKernelGGL(k_mlp, dim3(NN / 8), dim3(256), 0, stream,
                       F, W1, b1, W2, b2, DsqInv, F0, XA);

    float* Xc = XA; float* Xn = XB;
    for (int step = 0; step < PROP_STEPS; step++) {
        int fin = (step == PROP_STEPS - 1) ? 1 : 0;
        hipLaunchKernelGGL(k_prop, dim3(NN / 4), dim3(256), 0, stream,
                           Xc, F0, cols, deg, DsqInv, Dinv, Xn, out, fin);
        float* t1 = Xc; Xc = Xn; Xn = t1;
    }
}